// Round 4
// baseline (565.614 us; speedup 1.0000x reference)
//
#include <hip/hip_runtime.h>
#include <hip/hip_bf16.h>

// ---------------------------------------------------------------------------
// TransformerBlock: B=4, T=2048, D=1024, H=16, HD=64
// Round 4: revert gemm_bt8 (64x32 wave tile was LDS-read-bound: 6 ds_read per
// 8 MFMA vs 8 per 16). W2 grid starvation fixed by split-K=2 + fp32 atomicAdd
// into a pre-initialized d_out (= x1 + b2). Wave tile stays 64x64 everywhere.
// ---------------------------------------------------------------------------

typedef __bf16 bf16;
typedef __attribute__((ext_vector_type(8))) __bf16 bf16x8;
typedef __attribute__((ext_vector_type(4))) __bf16 bf16x4;
typedef __attribute__((ext_vector_type(4))) float floatx4;

#define EXPC 0.18033688011112042f  // 0.125 * log2(e)

__device__ __forceinline__ void async_cp16(const bf16* g, bf16* l) {
  __builtin_amdgcn_global_load_lds(
      (const __attribute__((address_space(1))) void*)g,
      (__attribute__((address_space(3))) void*)l, 16, 0, 0);
}

// ---------------------------------------------------------------------------
// Transpose + convert: W (K x N fp32) -> WT (N x K bf16). z picks the matrix.
// ---------------------------------------------------------------------------
__global__ __launch_bounds__(256) void transpose_cvt4(
    const float* __restrict__ S0, const float* __restrict__ S1,
    const float* __restrict__ S2, const float* __restrict__ S3,
    bf16* __restrict__ D0, bf16* __restrict__ D1, bf16* __restrict__ D2,
    bf16* __restrict__ D3, int K, int N) {
  const float* W = (blockIdx.z == 0) ? S0 : (blockIdx.z == 1) ? S1
                   : (blockIdx.z == 2) ? S2 : S3;
  bf16* WT = (blockIdx.z == 0) ? D0 : (blockIdx.z == 1) ? D1
             : (blockIdx.z == 2) ? D2 : D3;
  __shared__ bf16 tile[32][33];
  const int tn = blockIdx.x;
  const int tk = blockIdx.y;
  const int t = threadIdx.x;
  const int row = t >> 3;
  const int c4 = (t & 7) * 4;

  const float* src = W + (size_t)(tk * 32 + row) * N + tn * 32 + c4;
  float4 v = *(const float4*)src;
  tile[row][c4 + 0] = (bf16)v.x;
  tile[row][c4 + 1] = (bf16)v.y;
  tile[row][c4 + 2] = (bf16)v.z;
  tile[row][c4 + 3] = (bf16)v.w;
  __syncthreads();
  bf16x4 o;
  o[0] = tile[c4 + 0][row];
  o[1] = tile[c4 + 1][row];
  o[2] = tile[c4 + 2][row];
  o[3] = tile[c4 + 3][row];
  *(bf16x4*)(WT + (size_t)(tn * 32 + row) * K + tk * 32 + c4) = o;
}

__global__ __launch_bounds__(256) void transpose_cvt(
    const float* __restrict__ W, bf16* __restrict__ WT, int K, int N) {
  __shared__ bf16 tile[32][33];
  const int tn = blockIdx.x;
  const int tk = blockIdx.y;
  const int t = threadIdx.x;
  const int row = t >> 3;
  const int c4 = (t & 7) * 4;

  const float* src = W + (size_t)(tk * 32 + row) * N + tn * 32 + c4;
  float4 v = *(const float4*)src;
  tile[row][c4 + 0] = (bf16)v.x;
  tile[row][c4 + 1] = (bf16)v.y;
  tile[row][c4 + 2] = (bf16)v.z;
  tile[row][c4 + 3] = (bf16)v.w;
  __syncthreads();
  bf16x4 o;
  o[0] = tile[c4 + 0][row];
  o[1] = tile[c4 + 1][row];
  o[2] = tile[c4 + 2][row];
  o[3] = tile[c4 + 3][row];
  *(bf16x4*)(WT + (size_t)(tn * 32 + row) * K + tk * 32 + c4) = o;
}

// ---------------------------------------------------------------------------
// LayerNorm: one block per row of 1024. fp32 in -> bf16 out.
// ---------------------------------------------------------------------------
__global__ __launch_bounds__(256) void ln_kernel(
    const float* __restrict__ x, const float* __restrict__ gamma,
    const float* __restrict__ beta, bf16* __restrict__ out) {
  const int row = blockIdx.x;
  const int t = threadIdx.x;
  const float* xr = x + (size_t)row * 1024;
  float4 v4 = *(const float4*)(xr + t * 4);
  float a[4] = {v4.x, v4.y, v4.z, v4.w};
  float s = a[0] + a[1] + a[2] + a[3];
  float ss = a[0] * a[0] + a[1] * a[1] + a[2] * a[2] + a[3] * a[3];
  for (int off = 1; off < 64; off <<= 1) {
    s += __shfl_xor(s, off);
    ss += __shfl_xor(ss, off);
  }
  __shared__ float red[8];
  const int wid = t >> 6, lane = t & 63;
  if (lane == 0) { red[wid] = s; red[wid + 4] = ss; }
  __syncthreads();
  s = red[0] + red[1] + red[2] + red[3];
  ss = red[4] + red[5] + red[6] + red[7];
  const float mean = s * (1.0f / 1024.0f);
  const float var = ss * (1.0f / 1024.0f) - mean * mean;
  const float rstd = rsqrtf(var + 1e-5f);
  bf16x4 o;
  for (int j = 0; j < 4; ++j) {
    float g = gamma[t * 4 + j];
    float b = beta[t * 4 + j];
    o[j] = (bf16)((a[j] - mean) * rstd * g + b);
  }
  *(bf16x4*)(out + (size_t)row * 1024 + t * 4) = o;
}

// ---------------------------------------------------------------------------
// init: out[row, col] = resid[row, col] + bias[col]  (fp32, N=1024)
// ---------------------------------------------------------------------------
__global__ __launch_bounds__(256) void init_resid_bias(
    const float* __restrict__ resid, const float* __restrict__ bias,
    float* __restrict__ out) {
  const size_t row = blockIdx.x;
  const int t = threadIdx.x;
  float4 r = *(const float4*)(resid + row * 1024 + t * 4);
  float4 b = *(const float4*)(bias + t * 4);
  r.x += b.x; r.y += b.y; r.z += b.z; r.w += b.w;
  *(float4*)(out + row * 1024 + t * 4) = r;
}

__device__ __forceinline__ float gelu_f(float x) {
  const float c = 0.7978845608028654f;
  float u = c * (x + 0.044715f * x * x * x);
  return 0.5f * x * (1.0f + tanhf(u));
}

// ---------------------------------------------------------------------------
// GEMM (256 thr, 4 waves 2x2, each 64x64): C[M,N] = A[M,K] @ BT[N,K]^T over
// k in [kBegin, kEnd) (blockIdx.z * kChunk). 128x128 tile, BK=32, m97 staging.
// MODE 1: bf16 = gelu(C+bias); MODE 2: f32 = C+bias+resid; MODE 3: bf16 = C;
// MODE 4: f32 atomicAdd (split-K; out pre-initialized with resid+bias).
// ---------------------------------------------------------------------------
template <int MODE>
__global__ __launch_bounds__(256, 2) void gemm_bt(
    const bf16* __restrict__ A, const bf16* __restrict__ BT,
    const float* __restrict__ bias, const float* __restrict__ resid,
    void* __restrict__ out, int M, int N, int K, int kChunk) {
  __shared__ bf16 sA[128 * 32];
  __shared__ bf16 sB[128 * 32];
  const int t = threadIdx.x;
  const int lane = t & 63, wid = t >> 6;
  const int waveM = wid >> 1, waveN = wid & 1;
  const int quad = lane >> 4, l16 = lane & 15;
  const size_t m0 = (size_t)blockIdx.x * 128;
  const size_t n0 = (size_t)blockIdx.y * 128;
  const int kBegin = blockIdx.z * kChunk;
  const int kEnd = kBegin + kChunk;

  floatx4 acc[4][4] = {};

  const int srow = wid * 16 + (lane >> 2);
  const int scol = (lane & 3) * 8;
  const bf16* Ag = A + (m0 + srow) * (size_t)K + scol;
  const bf16* Bg = BT + (n0 + srow) * (size_t)K + scol;
  bf16* sAp = sA + wid * 512 + lane * 8;
  bf16* sBp = sB + wid * 512 + lane * 8;

  for (int k0 = kBegin; k0 < kEnd; k0 += 32) {
    __syncthreads();
    async_cp16(Ag + k0, sAp);
    async_cp16(Ag + (size_t)64 * K + k0, sAp + 64 * 32);
    async_cp16(Bg + k0, sBp);
    async_cp16(Bg + (size_t)64 * K + k0, sBp + 64 * 32);
    __syncthreads();
    bf16x8 af[4], bfv[4];
#pragma unroll
    for (int i = 0; i < 4; ++i)
      af[i] = *(const bf16x8*)&sA[(waveM * 64 + i * 16 + l16) * 32 + quad * 8];
#pragma unroll
    for (int i = 0; i < 4; ++i)
      bfv[i] = *(const bf16x8*)&sB[(waveN * 64 + i * 16 + l16) * 32 + quad * 8];
#pragma unroll
    for (int mt = 0; mt < 4; ++mt)
#pragma unroll
      for (int nt = 0; nt < 4; ++nt)
        acc[mt][nt] = __builtin_amdgcn_mfma_f32_16x16x32_bf16(
            af[mt], bfv[nt], acc[mt][nt], 0, 0, 0);
  }

#pragma unroll
  for (int mt = 0; mt < 4; ++mt) {
#pragma unroll
    for (int nt = 0; nt < 4; ++nt) {
      const size_t row_base = m0 + waveM * 64 + mt * 16 + quad * 4;
      const size_t col = n0 + waveN * 64 + nt * 16 + l16;
#pragma unroll
      for (int r = 0; r < 4; ++r) {
        const size_t row = row_base + r;
        float v = acc[mt][nt][r];
        if (MODE == 1) {
          v = gelu_f(v + bias[col]);
          ((bf16*)out)[row * N + col] = (bf16)v;
        } else if (MODE == 2) {
          v += bias[col] + resid[row * N + col];
          ((float*)out)[row * N + col] = v;
        } else if (MODE == 4) {
          atomicAdd(&((float*)out)[row * N + col], v);
        } else {
          ((bf16*)out)[row * N + col] = (bf16)v;
        }
      }
    }
  }
}

// ---------------------------------------------------------------------------
// Flash-style causal attention (unchanged from round 2).
// ---------------------------------------------------------------------------
__global__ __launch_bounds__(256) void attn_kernel(
    const bf16* __restrict__ QKV, bf16* __restrict__ O) {
  const int idx = blockIdx.x;
  const int qt = 31 - (idx >> 6);
  const int bh = idx & 63;
  const int b = bh >> 4, h = bh & 15;
  const int t = threadIdx.x;
  const int lane = t & 63, wid = t >> 6;
  const int quad = lane >> 4, l16 = lane & 15;

  __shared__ bf16 sQ[64][72];
  __shared__ bf16 sK[64][72];
  __shared__ bf16 sVt[64][72];
  __shared__ bf16 sP[4][16][72];

  const size_t qbase = (size_t)b * 2048 * 3072 + (size_t)h * 64;
  const size_t kbase = qbase + 1024;
  const size_t vbase = qbase + 2048;
  const int q0 = qt * 64;

  for (int c = t; c < 512; c += 256) {
    int row = c >> 3, sub = (c & 7) * 8;
    *(bf16x8*)&sQ[row][sub] =
        *(const bf16x8*)(QKV + qbase + (size_t)(q0 + row) * 3072 + sub);
  }
  __syncthreads();

  bf16x8 aq[2];
  aq[0] = *(const bf16x8*)&sQ[wid * 16 + l16][quad * 8];
  aq[1] = *(const bf16x8*)&sQ[wid * 16 + l16][32 + quad * 8];

  float l_part[4] = {0.f, 0.f, 0.f, 0.f};
  floatx4 o_acc[4] = {};

  for (int kt = 0; kt <= qt; ++kt) {
    __syncthreads();
    const int k0 = kt * 64;
    for (int c = t; c < 512; c += 256) {
      int row = c >> 3, sub = (c & 7) * 8;
      *(bf16x8*)&sK[row][sub] =
          *(const bf16x8*)(QKV + kbase + (size_t)(k0 + row) * 3072 + sub);
      bf16x8 v8 = *(const bf16x8*)(QKV + vbase + (size_t)(k0 + row) * 3072 + sub);
#pragma unroll
      for (int j = 0; j < 8; ++j)
        sVt[sub + j][row ^ (sub & 56)] = v8[j];
    }
    __syncthreads();

    float p[4][4];
#pragma unroll
    for (int nt = 0; nt < 4; ++nt) {
      floatx4 acc = {};
#pragma unroll
      for (int ks = 0; ks < 2; ++ks) {
        bf16x8 bk = *(const bf16x8*)&sK[nt * 16 + l16][ks * 32 + quad * 8];
        acc = __builtin_amdgcn_mfma_f32_16x16x32_bf16(aq[ks], bk, acc, 0, 0, 0);
      }
#pragma unroll
      for (int r = 0; r < 4; ++r) p[nt][r] = exp2f(acc[r] * EXPC);
    }

    if (kt == qt) {
      const int qrow_base = q0 + wid * 16 + quad * 4;
#pragma unroll
      for (int nt = 0; nt < 4; ++nt) {
        const int kk = k0 + nt * 16 + l16;
#pragma unroll
        for (int r = 0; r < 4; ++r)
          if (kk > qrow_base + r) p[nt][r] = 0.f;
      }
    }

#pragma unroll
    for (int nt = 0; nt < 4; ++nt)
#pragma unroll
      for (int r = 0; r < 4; ++r) {
        l_part[r] += p[nt][r];
        sP[wid][quad * 4 + r][nt * 16 + l16] = (bf16)p[nt][r];
      }

    bf16x8 ap[2];
    ap[0] = *(const bf16x8*)&sP[wid][l16][quad * 8];
    ap[1] = *(const bf16x8*)&sP[wid][l16][32 + quad * 8];
#pragma unroll
    for (int nt = 0; nt < 4; ++nt) {
      const int r2 = nt * 16 + l16;
#pragma unroll
      for (int ks = 0; ks < 2; ++ks) {
        bf16x8 bv =
            *(const bf16x8*)&sVt[r2][(ks * 32 + quad * 8) ^ (r2 & 56)];
        o_acc[nt] =
            __builtin_amdgcn_mfma_f32_16x16x32_bf16(ap[ks], bv, o_acc[nt], 0, 0, 0);
      }
    }
  }

#pragma unroll
  for (int off = 1; off < 16; off <<= 1)
#pragma unroll
    for (int r = 0; r < 4; ++r) l_part[r] += __shfl_xor(l_part[r], off);
  float inv[4];
#pragma unroll
  for (int r = 0; r < 4; ++r) inv[r] = 1.0f / l_part[r];

#pragma unroll
  for (int nt = 0; nt < 4; ++nt)
#pragma unroll
    for (int r = 0; r < 4; ++r) {
      const size_t row = (size_t)b * 2048 + q0 + wid * 16 + quad * 4 + r;
      const size_t col = (size_t)h * 64 + nt * 16 + l16;
      O[row * 1024 + col] = (bf16)(o_acc[nt][r] * inv[r]);
    }
}

// ---------------------------------------------------------------------------
// Launch
// ---------------------------------------------------------------------------
extern "C" void kernel_launch(void* const* d_in, const int* in_sizes, int n_in,
                              void* d_out, int out_size, void* d_ws, size_t ws_size,
                              hipStream_t stream) {
  const float* x = (const float*)d_in[0];
  const float* Wq = (const float*)d_in[1];
  const float* Wk = (const float*)d_in[2];
  const float* Wv = (const float*)d_in[3];
  const float* Wo = (const float*)d_in[4];
  const float* bo = (const float*)d_in[5];
  const float* W1 = (const float*)d_in[6];
  const float* b1 = (const float*)d_in[7];
  const float* W2 = (const float*)d_in[8];
  const float* b2 = (const float*)d_in[9];
  const float* gamma1 = (const float*)d_in[10];
  const float* beta1 = (const float*)d_in[11];
  const float* gamma2 = (const float*)d_in[12];
  const float* beta2 = (const float*)d_in[13];

  char* ws = (char*)d_ws;
  const size_t MB = (size_t)1 << 20;
  bf16* WqkvT = (bf16*)(ws + 0 * MB);
  bf16* WoT = (bf16*)(ws + 6 * MB);
  bf16* W1T = (bf16*)(ws + 8 * MB);
  bf16* W2T = (bf16*)(ws + 16 * MB);
  bf16* h1  = (bf16*)(ws + 24 * MB);
  bf16* QKVb = (bf16*)(ws + 40 * MB);
  bf16* attnb = (bf16*)(ws + 88 * MB);
  float* x1 = (float*)(ws + 104 * MB);
  bf16* h2  = (bf16*)(ws + 136 * MB);
  bf16* midb = (bf16*)(ws + 152 * MB);

  dim3 blk(256);

  transpose_cvt4<<<dim3(32, 32, 4), blk, 0, stream>>>(
      Wq, Wk, Wv, Wo, WqkvT, WqkvT + (size_t)1024 * 1024,
      WqkvT + (size_t)2048 * 1024, WoT, 1024, 1024);
  transpose_cvt<<<dim3(128, 32), blk, 0, stream>>>(W1, W1T, 1024, 4096);
  transpose_cvt<<<dim3(32, 128), blk, 0, stream>>>(W2, W2T, 4096, 1024);

  ln_kernel<<<8192, blk, 0, stream>>>(x, gamma1, beta1, h1);

  // fused QKV projection: [Q|K|V] = h1 @ [Wq|Wk|Wv]
  gemm_bt<3><<<dim3(64, 24), blk, 0, stream>>>(h1, WqkvT, nullptr, nullptr,
                                               QKVb, 8192, 3072, 1024, 1024);

  attn_kernel<<<dim3(2048), blk, 0, stream>>>(QKVb, attnb);

  // x1 = x + attn @ Wo + bo
  gemm_bt<2><<<dim3(64, 8), blk, 0, stream>>>(attnb, WoT, bo, x, x1,
                                              8192, 1024, 1024, 1024);

  ln_kernel<<<8192, blk, 0, stream>>>(x1, gamma2, beta2, h2);

  // mid = gelu(h2 @ W1 + b1)
  gemm_bt<1><<<dim3(64, 32), blk, 0, stream>>>(h2, W1T, b1, nullptr, midb,
                                               8192, 4096, 1024, 1024);

  // out = x1 + b2 (init), then += mid @ W2 via split-K=2 atomic GEMM
  init_resid_bias<<<8192, blk, 0, stream>>>(x1, b2, (float*)d_out);
  gemm_bt<4><<<dim3(64, 8, 2), blk, 0, stream>>>(midb, W2T, nullptr, nullptr,
                                                 d_out, 8192, 1024, 4096, 2048);
}

// Round 5
// 496.619 us; speedup vs baseline: 1.1389x; 1.1389x over previous
//
#include <hip/hip_runtime.h>
#include <hip/hip_bf16.h>

// ---------------------------------------------------------------------------
// TransformerBlock: B=4, T=2048, D=1024, H=16, HD=64
// Round 5: revert split-K atomics (64MB of scalar atomicAdds cost more than
// occupancy gained). Grid-starved GEMMs (Wo, W2: 512 blocks = 2 blocks/CU)
// instead get BK=128: 4x fewer vmcnt(0) barrier drains (128->32 for W2),
// 64KB LDS/block (2 blocks still fit in 160KB; grid caps at 2 anyway).
// BK>=64 needs XOR group swizzle (gsrc = gp ^ (row&7)) done on the GLOBAL
// gather side -- global_load_lds dst must stay linear (wave base + lane*16).
// QKV/W1 keep proven BK=32 (SW=0, staging byte-identical to round 2).
// ---------------------------------------------------------------------------

typedef __bf16 bf16;
typedef __attribute__((ext_vector_type(8))) __bf16 bf16x8;
typedef __attribute__((ext_vector_type(4))) __bf16 bf16x4;
typedef __attribute__((ext_vector_type(4))) float floatx4;

#define EXPC 0.18033688011112042f  // 0.125 * log2(e)

__device__ __forceinline__ void async_cp16(const bf16* g, bf16* l) {
  __builtin_amdgcn_global_load_lds(
      (const __attribute__((address_space(1))) void*)g,
      (__attribute__((address_space(3))) void*)l, 16, 0, 0);
}

// ---------------------------------------------------------------------------
// Transpose + convert: W (K x N fp32) -> WT (N x K bf16). z picks the matrix.
// ---------------------------------------------------------------------------
__global__ __launch_bounds__(256) void transpose_cvt4(
    const float* __restrict__ S0, const float* __restrict__ S1,
    const float* __restrict__ S2, const float* __restrict__ S3,
    bf16* __restrict__ D0, bf16* __restrict__ D1, bf16* __restrict__ D2,
    bf16* __restrict__ D3, int K, int N) {
  const float* W = (blockIdx.z == 0) ? S0 : (blockIdx.z == 1) ? S1
                   : (blockIdx.z == 2) ? S2 : S3;
  bf16* WT = (blockIdx.z == 0) ? D0 : (blockIdx.z == 1) ? D1
             : (blockIdx.z == 2) ? D2 : D3;
  __shared__ bf16 tile[32][33];
  const int tn = blockIdx.x;
  const int tk = blockIdx.y;
  const int t = threadIdx.x;
  const int row = t >> 3;
  const int c4 = (t & 7) * 4;

  const float* src = W + (size_t)(tk * 32 + row) * N + tn * 32 + c4;
  float4 v = *(const float4*)src;
  tile[row][c4 + 0] = (bf16)v.x;
  tile[row][c4 + 1] = (bf16)v.y;
  tile[row][c4 + 2] = (bf16)v.z;
  tile[row][c4 + 3] = (bf16)v.w;
  __syncthreads();
  bf16x4 o;
  o[0] = tile[c4 + 0][row];
  o[1] = tile[c4 + 1][row];
  o[2] = tile[c4 + 2][row];
  o[3] = tile[c4 + 3][row];
  *(bf16x4*)(WT + (size_t)(tn * 32 + row) * K + tk * 32 + c4) = o;
}

__global__ __launch_bounds__(256) void transpose_cvt(
    const float* __restrict__ W, bf16* __restrict__ WT, int K, int N) {
  __shared__ bf16 tile[32][33];
  const int tn = blockIdx.x;
  const int tk = blockIdx.y;
  const int t = threadIdx.x;
  const int row = t >> 3;
  const int c4 = (t & 7) * 4;

  const float* src = W + (size_t)(tk * 32 + row) * N + tn * 32 + c4;
  float4 v = *(const float4*)src;
  tile[row][c4 + 0] = (bf16)v.x;
  tile[row][c4 + 1] = (bf16)v.y;
  tile[row][c4 + 2] = (bf16)v.z;
  tile[row][c4 + 3] = (bf16)v.w;
  __syncthreads();
  bf16x4 o;
  o[0] = tile[c4 + 0][row];
  o[1] = tile[c4 + 1][row];
  o[2] = tile[c4 + 2][row];
  o[3] = tile[c4 + 3][row];
  *(bf16x4*)(WT + (size_t)(tn * 32 + row) * K + tk * 32 + c4) = o;
}

// ---------------------------------------------------------------------------
// LayerNorm: one block per row of 1024. fp32 in -> bf16 out.
// ---------------------------------------------------------------------------
__global__ __launch_bounds__(256) void ln_kernel(
    const float* __restrict__ x, const float* __restrict__ gamma,
    const float* __restrict__ beta, bf16* __restrict__ out) {
  const int row = blockIdx.x;
  const int t = threadIdx.x;
  const float* xr = x + (size_t)row * 1024;
  float4 v4 = *(const float4*)(xr + t * 4);
  float a[4] = {v4.x, v4.y, v4.z, v4.w};
  float s = a[0] + a[1] + a[2] + a[3];
  float ss = a[0] * a[0] + a[1] * a[1] + a[2] * a[2] + a[3] * a[3];
  for (int off = 1; off < 64; off <<= 1) {
    s += __shfl_xor(s, off);
    ss += __shfl_xor(ss, off);
  }
  __shared__ float red[8];
  const int wid = t >> 6, lane = t & 63;
  if (lane == 0) { red[wid] = s; red[wid + 4] = ss; }
  __syncthreads();
  s = red[0] + red[1] + red[2] + red[3];
  ss = red[4] + red[5] + red[6] + red[7];
  const float mean = s * (1.0f / 1024.0f);
  const float var = ss * (1.0f / 1024.0f) - mean * mean;
  const float rstd = rsqrtf(var + 1e-5f);
  bf16x4 o;
  for (int j = 0; j < 4; ++j) {
    float g = gamma[t * 4 + j];
    float b = beta[t * 4 + j];
    o[j] = (bf16)((a[j] - mean) * rstd * g + b);
  }
  *(bf16x4*)(out + (size_t)row * 1024 + t * 4) = o;
}

__device__ __forceinline__ float gelu_f(float x) {
  const float c = 0.7978845608028654f;
  float u = c * (x + 0.044715f * x * x * x);
  return 0.5f * x * (1.0f + tanhf(u));
}

// ---------------------------------------------------------------------------
// GEMM (256 thr, 4 waves 2x2, each 64x64): C[M,N] = A[M,K] @ BT[N,K]^T.
// 128x128 tile, templated BK (32 for block-rich shapes, 128 for grid-starved).
// BK>=64: 16B groups XOR-swizzled via the global gather (LDS dst stays
// linear for global_load_lds); fragment reads land 2-way (free).
// MODE 1: bf16 = gelu(C+bias); MODE 2: f32 = C+bias+resid; MODE 3: bf16 = C.
// ---------------------------------------------------------------------------
template <int MODE, int BK>
__global__ __launch_bounds__(256, 2) void gemm_bt(
    const bf16* __restrict__ A, const bf16* __restrict__ BT,
    const float* __restrict__ bias, const float* __restrict__ resid,
    void* __restrict__ out, int M, int N, int K) {
  __shared__ bf16 sA[128 * BK];
  __shared__ bf16 sB[128 * BK];
  constexpr int GPR = BK / 8;    // 16B groups per row
  constexpr int CPT = GPR / 2;   // staging iterations (chunks per thread)
  constexpr int RPI = 256 / GPR; // rows staged per iteration
  constexpr int SW = (BK >= 64) ? 7 : 0;  // group swizzle mask

  const int t = threadIdx.x;
  const int lane = t & 63, wid = t >> 6;
  const int waveM = wid >> 1, waveN = wid & 1;
  const int quad = lane >> 4, l16 = lane & 15;
  const size_t m0 = (size_t)blockIdx.x * 128;
  const size_t n0 = (size_t)blockIdx.y * 128;

  floatx4 acc[4][4] = {};

  // staging map: chunk c = it*256 + t -> row = it*RPI + t/GPR, group gp = t%GPR
  // data gathered from global group gsrc = gp ^ (row & SW); LDS stays linear.
  const int r0 = t / GPR;
  const int gp = t % GPR;
  const int gsrc = gp ^ (r0 & SW);
  const bf16* Ag = A + (m0 + r0) * (size_t)K + gsrc * 8;
  const bf16* Bg = BT + (n0 + r0) * (size_t)K + gsrc * 8;
  bf16* sAp = sA + t * 8;
  bf16* sBp = sB + t * 8;

  for (int k0 = 0; k0 < K; k0 += BK) {
    __syncthreads();
#pragma unroll
    for (int it = 0; it < CPT; ++it) {
      async_cp16(Ag + k0 + (size_t)(it * RPI) * K, sAp + it * 2048);
      async_cp16(Bg + k0 + (size_t)(it * RPI) * K, sBp + it * 2048);
    }
    __syncthreads();
#pragma unroll
    for (int ks = 0; ks < BK / 32; ++ks) {
      bf16x8 af[4], bfv[4];
#pragma unroll
      for (int i = 0; i < 4; ++i) {
        const int rowA = waveM * 64 + i * 16 + l16;
        const int g = ((ks * 4 + quad) ^ (l16 & SW)) * 8;
        af[i] = *(const bf16x8*)&sA[rowA * BK + g];
        const int rowB = waveN * 64 + i * 16 + l16;
        bfv[i] = *(const bf16x8*)&sB[rowB * BK + g];
      }
#pragma unroll
      for (int mt = 0; mt < 4; ++mt)
#pragma unroll
        for (int nt = 0; nt < 4; ++nt)
          acc[mt][nt] = __builtin_amdgcn_mfma_f32_16x16x32_bf16(
              af[mt], bfv[nt], acc[mt][nt], 0, 0, 0);
    }
  }

#pragma unroll
  for (int mt = 0; mt < 4; ++mt) {
#pragma unroll
    for (int nt = 0; nt < 4; ++nt) {
      const size_t row_base = m0 + waveM * 64 + mt * 16 + quad * 4;
      const size_t col = n0 + waveN * 64 + nt * 16 + l16;
#pragma unroll
      for (int r = 0; r < 4; ++r) {
        const size_t row = row_base + r;
        float v = acc[mt][nt][r];
        if (MODE == 1) {
          v = gelu_f(v + bias[col]);
          ((bf16*)out)[row * N + col] = (bf16)v;
        } else if (MODE == 2) {
          v += bias[col] + resid[row * N + col];
          ((float*)out)[row * N + col] = v;
        } else {
          ((bf16*)out)[row * N + col] = (bf16)v;
        }
      }
    }
  }
}

// ---------------------------------------------------------------------------
// Flash-style causal attention (unchanged from round 2).
// ---------------------------------------------------------------------------
__global__ __launch_bounds__(256) void attn_kernel(
    const bf16* __restrict__ QKV, bf16* __restrict__ O) {
  const int idx = blockIdx.x;
  const int qt = 31 - (idx >> 6);
  const int bh = idx & 63;
  const int b = bh >> 4, h = bh & 15;
  const int t = threadIdx.x;
  const int lane = t & 63, wid = t >> 6;
  const int quad = lane >> 4, l16 = lane & 15;

  __shared__ bf16 sQ[64][72];
  __shared__ bf16 sK[64][72];
  __shared__ bf16 sVt[64][72];
  __shared__ bf16 sP[4][16][72];

  const size_t qbase = (size_t)b * 2048 * 3072 + (size_t)h * 64;
  const size_t kbase = qbase + 1024;
  const size_t vbase = qbase + 2048;
  const int q0 = qt * 64;

  for (int c = t; c < 512; c += 256) {
    int row = c >> 3, sub = (c & 7) * 8;
    *(bf16x8*)&sQ[row][sub] =
        *(const bf16x8*)(QKV + qbase + (size_t)(q0 + row) * 3072 + sub);
  }
  __syncthreads();

  bf16x8 aq[2];
  aq[0] = *(const bf16x8*)&sQ[wid * 16 + l16][quad * 8];
  aq[1] = *(const bf16x8*)&sQ[wid * 16 + l16][32 + quad * 8];

  float l_part[4] = {0.f, 0.f, 0.f, 0.f};
  floatx4 o_acc[4] = {};

  for (int kt = 0; kt <= qt; ++kt) {
    __syncthreads();
    const int k0 = kt * 64;
    for (int c = t; c < 512; c += 256) {
      int row = c >> 3, sub = (c & 7) * 8;
      *(bf16x8*)&sK[row][sub] =
          *(const bf16x8*)(QKV + kbase + (size_t)(k0 + row) * 3072 + sub);
      bf16x8 v8 = *(const bf16x8*)(QKV + vbase + (size_t)(k0 + row) * 3072 + sub);
#pragma unroll
      for (int j = 0; j < 8; ++j)
        sVt[sub + j][row ^ (sub & 56)] = v8[j];
    }
    __syncthreads();

    float p[4][4];
#pragma unroll
    for (int nt = 0; nt < 4; ++nt) {
      floatx4 acc = {};
#pragma unroll
      for (int ks = 0; ks < 2; ++ks) {
        bf16x8 bk = *(const bf16x8*)&sK[nt * 16 + l16][ks * 32 + quad * 8];
        acc = __builtin_amdgcn_mfma_f32_16x16x32_bf16(aq[ks], bk, acc, 0, 0, 0);
      }
#pragma unroll
      for (int r = 0; r < 4; ++r) p[nt][r] = exp2f(acc[r] * EXPC);
    }

    if (kt == qt) {
      const int qrow_base = q0 + wid * 16 + quad * 4;
#pragma unroll
      for (int nt = 0; nt < 4; ++nt) {
        const int kk = k0 + nt * 16 + l16;
#pragma unroll
        for (int r = 0; r < 4; ++r)
          if (kk > qrow_base + r) p[nt][r] = 0.f;
      }
    }

#pragma unroll
    for (int nt = 0; nt < 4; ++nt)
#pragma unroll
      for (int r = 0; r < 4; ++r) {
        l_part[r] += p[nt][r];
        sP[wid][quad * 4 + r][nt * 16 + l16] = (bf16)p[nt][r];
      }

    bf16x8 ap[2];
    ap[0] = *(const bf16x8*)&sP[wid][l16][quad * 8];
    ap[1] = *(const bf16x8*)&sP[wid][l16][32 + quad * 8];
#pragma unroll
    for (int nt = 0; nt < 4; ++nt) {
      const int r2 = nt * 16 + l16;
#pragma unroll
      for (int ks = 0; ks < 2; ++ks) {
        bf16x8 bv =
            *(const bf16x8*)&sVt[r2][(ks * 32 + quad * 8) ^ (r2 & 56)];
        o_acc[nt] =
            __builtin_amdgcn_mfma_f32_16x16x32_bf16(ap[ks], bv, o_acc[nt], 0, 0, 0);
      }
    }
  }

#pragma unroll
  for (int off = 1; off < 16; off <<= 1)
#pragma unroll
    for (int r = 0; r < 4; ++r) l_part[r] += __shfl_xor(l_part[r], off);
  float inv[4];
#pragma unroll
  for (int r = 0; r < 4; ++r) inv[r] = 1.0f / l_part[r];

#pragma unroll
  for (int nt = 0; nt < 4; ++nt)
#pragma unroll
    for (int r = 0; r < 4; ++r) {
      const size_t row = (size_t)b * 2048 + q0 + wid * 16 + quad * 4 + r;
      const size_t col = (size_t)h * 64 + nt * 16 + l16;
      O[row * 1024 + col] = (bf16)(o_acc[nt][r] * inv[r]);
    }
}

// ---------------------------------------------------------------------------
// Launch
// ---------------------------------------------------------------------------
extern "C" void kernel_launch(void* const* d_in, const int* in_sizes, int n_in,
                              void* d_out, int out_size, void* d_ws, size_t ws_size,
                              hipStream_t stream) {
  const float* x = (const float*)d_in[0];
  const float* Wq = (const float*)d_in[1];
  const float* Wk = (const float*)d_in[2];
  const float* Wv = (const float*)d_in[3];
  const float* Wo = (const float*)d_in[4];
  const float* bo = (const float*)d_in[5];
  const float* W1 = (const float*)d_in[6];
  const float* b1 = (const float*)d_in[7];
  const float* W2 = (const float*)d_in[8];
  const float* b2 = (const float*)d_in[9];
  const float* gamma1 = (const float*)d_in[10];
  const float* beta1 = (const float*)d_in[11];
  const float* gamma2 = (const float*)d_in[12];
  const float* beta2 = (const float*)d_in[13];

  char* ws = (char*)d_ws;
  const size_t MB = (size_t)1 << 20;
  bf16* WqkvT = (bf16*)(ws + 0 * MB);
  bf16* WoT = (bf16*)(ws + 6 * MB);
  bf16* W1T = (bf16*)(ws + 8 * MB);
  bf16* W2T = (bf16*)(ws + 16 * MB);
  bf16* h1  = (bf16*)(ws + 24 * MB);
  bf16* QKVb = (bf16*)(ws + 40 * MB);
  bf16* attnb = (bf16*)(ws + 88 * MB);
  float* x1 = (float*)(ws + 104 * MB);
  bf16* h2  = (bf16*)(ws + 136 * MB);
  bf16* midb = (bf16*)(ws + 152 * MB);

  dim3 blk(256);

  transpose_cvt4<<<dim3(32, 32, 4), blk, 0, stream>>>(
      Wq, Wk, Wv, Wo, WqkvT, WqkvT + (size_t)1024 * 1024,
      WqkvT + (size_t)2048 * 1024, WoT, 1024, 1024);
  transpose_cvt<<<dim3(128, 32), blk, 0, stream>>>(W1, W1T, 1024, 4096);
  transpose_cvt<<<dim3(32, 128), blk, 0, stream>>>(W2, W2T, 4096, 1024);

  ln_kernel<<<8192, blk, 0, stream>>>(x, gamma1, beta1, h1);

  // fused QKV projection: [Q|K|V] = h1 @ [Wq|Wk|Wv]  (block-rich: BK=32)
  gemm_bt<3, 32><<<dim3(64, 24), blk, 0, stream>>>(h1, WqkvT, nullptr, nullptr,
                                                   QKVb, 8192, 3072, 1024);

  attn_kernel<<<dim3(2048), blk, 0, stream>>>(QKVb, attnb);

  // x1 = x + attn @ Wo + bo  (grid-starved: BK=128, 8 barrier drains)
  gemm_bt<2, 128><<<dim3(64, 8), blk, 0, stream>>>(attnb, WoT, bo, x, x1,
                                                   8192, 1024, 1024);

  ln_kernel<<<8192, blk, 0, stream>>>(x1, gamma2, beta2, h2);

  // mid = gelu(h2 @ W1 + b1)  (block-rich: BK=32)
  gemm_bt<1, 32><<<dim3(64, 32), blk, 0, stream>>>(h2, W1T, b1, nullptr, midb,
                                                   8192, 4096, 1024);

  // out = x1 + mid @ W2 + b2  (grid-starved: BK=128, 32 barrier drains)
  gemm_bt<2, 128><<<dim3(64, 8), blk, 0, stream>>>(midb, W2T, b2, x1, d_out,
                                                   8192, 1024, 4096);
}

// Round 6
// 464.338 us; speedup vs baseline: 1.2181x; 1.0695x over previous
//
#include <hip/hip_runtime.h>
#include <hip/hip_bf16.h>

// ---------------------------------------------------------------------------
// TransformerBlock: B=4, T=2048, D=1024, H=16, HD=64
// Round 6: (1) fast gelu: tanh(u) = via t=exp2(2u*log2e), gelu = x*t/(t+1)
// (v_exp+v_rcp+4ops vs ~28-op libm tanhf) -- W1 epilogue was 46% VALUBusy.
// (2) BK=64 for block-rich GEMMs (QKV, W1): halves barrier drains, 32KB LDS
// keeps ~3 blocks/CU (the BK=128 occupancy cliff is at 64KB).
// Wo/W2 stay BK=128 (grid-capped at 2 blocks/CU; drains dominate there).
// ---------------------------------------------------------------------------

typedef __bf16 bf16;
typedef __attribute__((ext_vector_type(8))) __bf16 bf16x8;
typedef __attribute__((ext_vector_type(4))) __bf16 bf16x4;
typedef __attribute__((ext_vector_type(4))) float floatx4;

#define EXPC 0.18033688011112042f  // 0.125 * log2(e)

__device__ __forceinline__ void async_cp16(const bf16* g, bf16* l) {
  __builtin_amdgcn_global_load_lds(
      (const __attribute__((address_space(1))) void*)g,
      (__attribute__((address_space(3))) void*)l, 16, 0, 0);
}

// ---------------------------------------------------------------------------
// Transpose + convert: W (K x N fp32) -> WT (N x K bf16). z picks the matrix.
// ---------------------------------------------------------------------------
__global__ __launch_bounds__(256) void transpose_cvt4(
    const float* __restrict__ S0, const float* __restrict__ S1,
    const float* __restrict__ S2, const float* __restrict__ S3,
    bf16* __restrict__ D0, bf16* __restrict__ D1, bf16* __restrict__ D2,
    bf16* __restrict__ D3, int K, int N) {
  const float* W = (blockIdx.z == 0) ? S0 : (blockIdx.z == 1) ? S1
                   : (blockIdx.z == 2) ? S2 : S3;
  bf16* WT = (blockIdx.z == 0) ? D0 : (blockIdx.z == 1) ? D1
             : (blockIdx.z == 2) ? D2 : D3;
  __shared__ bf16 tile[32][33];
  const int tn = blockIdx.x;
  const int tk = blockIdx.y;
  const int t = threadIdx.x;
  const int row = t >> 3;
  const int c4 = (t & 7) * 4;

  const float* src = W + (size_t)(tk * 32 + row) * N + tn * 32 + c4;
  float4 v = *(const float4*)src;
  tile[row][c4 + 0] = (bf16)v.x;
  tile[row][c4 + 1] = (bf16)v.y;
  tile[row][c4 + 2] = (bf16)v.z;
  tile[row][c4 + 3] = (bf16)v.w;
  __syncthreads();
  bf16x4 o;
  o[0] = tile[c4 + 0][row];
  o[1] = tile[c4 + 1][row];
  o[2] = tile[c4 + 2][row];
  o[3] = tile[c4 + 3][row];
  *(bf16x4*)(WT + (size_t)(tn * 32 + row) * K + tk * 32 + c4) = o;
}

__global__ __launch_bounds__(256) void transpose_cvt(
    const float* __restrict__ W, bf16* __restrict__ WT, int K, int N) {
  __shared__ bf16 tile[32][33];
  const int tn = blockIdx.x;
  const int tk = blockIdx.y;
  const int t = threadIdx.x;
  const int row = t >> 3;
  const int c4 = (t & 7) * 4;

  const float* src = W + (size_t)(tk * 32 + row) * N + tn * 32 + c4;
  float4 v = *(const float4*)src;
  tile[row][c4 + 0] = (bf16)v.x;
  tile[row][c4 + 1] = (bf16)v.y;
  tile[row][c4 + 2] = (bf16)v.z;
  tile[row][c4 + 3] = (bf16)v.w;
  __syncthreads();
  bf16x4 o;
  o[0] = tile[c4 + 0][row];
  o[1] = tile[c4 + 1][row];
  o[2] = tile[c4 + 2][row];
  o[3] = tile[c4 + 3][row];
  *(bf16x4*)(WT + (size_t)(tn * 32 + row) * K + tk * 32 + c4) = o;
}

// ---------------------------------------------------------------------------
// LayerNorm: one block per row of 1024. fp32 in -> bf16 out.
// ---------------------------------------------------------------------------
__global__ __launch_bounds__(256) void ln_kernel(
    const float* __restrict__ x, const float* __restrict__ gamma,
    const float* __restrict__ beta, bf16* __restrict__ out) {
  const int row = blockIdx.x;
  const int t = threadIdx.x;
  const float* xr = x + (size_t)row * 1024;
  float4 v4 = *(const float4*)(xr + t * 4);
  float a[4] = {v4.x, v4.y, v4.z, v4.w};
  float s = a[0] + a[1] + a[2] + a[3];
  float ss = a[0] * a[0] + a[1] * a[1] + a[2] * a[2] + a[3] * a[3];
  for (int off = 1; off < 64; off <<= 1) {
    s += __shfl_xor(s, off);
    ss += __shfl_xor(ss, off);
  }
  __shared__ float red[8];
  const int wid = t >> 6, lane = t & 63;
  if (lane == 0) { red[wid] = s; red[wid + 4] = ss; }
  __syncthreads();
  s = red[0] + red[1] + red[2] + red[3];
  ss = red[4] + red[5] + red[6] + red[7];
  const float mean = s * (1.0f / 1024.0f);
  const float var = ss * (1.0f / 1024.0f) - mean * mean;
  const float rstd = rsqrtf(var + 1e-5f);
  bf16x4 o;
  for (int j = 0; j < 4; ++j) {
    float g = gamma[t * 4 + j];
    float b = beta[t * 4 + j];
    o[j] = (bf16)((a[j] - mean) * rstd * g + b);
  }
  *(bf16x4*)(out + (size_t)row * 1024 + t * 4) = o;
}

// fast exact-form tanh-gelu: tanh(u) = 1 - 2/(e^{2u}+1); gelu = x*t/(t+1),
// t = exp2(2u*log2e). u clamped +-10 (tanh saturated; inputs sigma~0.64).
__device__ __forceinline__ float gelu_f(float x) {
  const float c = 0.7978845608028654f;
  float u = c * (x + 0.044715f * x * x * x);
  u = fminf(fmaxf(u, -10.0f), 10.0f);
  float t = __builtin_exp2f(u * 2.8853900817779268f);  // e^{2u}
  return x * t * __builtin_amdgcn_rcpf(t + 1.0f);
}

// ---------------------------------------------------------------------------
// GEMM (256 thr, 4 waves 2x2, each 64x64): C[M,N] = A[M,K] @ BT[N,K]^T.
// 128x128 tile, templated BK: 64 for block-rich shapes (3 blocks/CU, 16
// drains), 128 for grid-starved (2 blocks/CU cap, 8-32 drains).
// BK>=64: 16B groups XOR-swizzled via the global gather (LDS dst stays
// linear for global_load_lds); fragment reads land 2-way (free).
// MODE 1: bf16 = gelu(C+bias); MODE 2: f32 = C+bias+resid; MODE 3: bf16 = C.
// ---------------------------------------------------------------------------
template <int MODE, int BK>
__global__ __launch_bounds__(256, 2) void gemm_bt(
    const bf16* __restrict__ A, const bf16* __restrict__ BT,
    const float* __restrict__ bias, const float* __restrict__ resid,
    void* __restrict__ out, int M, int N, int K) {
  __shared__ bf16 sA[128 * BK];
  __shared__ bf16 sB[128 * BK];
  constexpr int GPR = BK / 8;    // 16B groups per row
  constexpr int CPT = GPR / 2;   // staging iterations (chunks per thread)
  constexpr int RPI = 256 / GPR; // rows staged per iteration
  constexpr int SW = (BK >= 64) ? 7 : 0;  // group swizzle mask

  const int t = threadIdx.x;
  const int lane = t & 63, wid = t >> 6;
  const int waveM = wid >> 1, waveN = wid & 1;
  const int quad = lane >> 4, l16 = lane & 15;
  const size_t m0 = (size_t)blockIdx.x * 128;
  const size_t n0 = (size_t)blockIdx.y * 128;

  floatx4 acc[4][4] = {};

  // staging map: chunk c = it*256 + t -> row = it*RPI + t/GPR, group gp = t%GPR
  // data gathered from global group gsrc = gp ^ (row & SW); LDS stays linear.
  const int r0 = t / GPR;
  const int gp = t % GPR;
  const int gsrc = gp ^ (r0 & SW);
  const bf16* Ag = A + (m0 + r0) * (size_t)K + gsrc * 8;
  const bf16* Bg = BT + (n0 + r0) * (size_t)K + gsrc * 8;
  bf16* sAp = sA + t * 8;
  bf16* sBp = sB + t * 8;

  for (int k0 = 0; k0 < K; k0 += BK) {
    __syncthreads();
#pragma unroll
    for (int it = 0; it < CPT; ++it) {
      async_cp16(Ag + k0 + (size_t)(it * RPI) * K, sAp + it * 2048);
      async_cp16(Bg + k0 + (size_t)(it * RPI) * K, sBp + it * 2048);
    }
    __syncthreads();
#pragma unroll
    for (int ks = 0; ks < BK / 32; ++ks) {
      bf16x8 af[4], bfv[4];
#pragma unroll
      for (int i = 0; i < 4; ++i) {
        const int rowA = waveM * 64 + i * 16 + l16;
        const int g = ((ks * 4 + quad) ^ (l16 & SW)) * 8;
        af[i] = *(const bf16x8*)&sA[rowA * BK + g];
        const int rowB = waveN * 64 + i * 16 + l16;
        bfv[i] = *(const bf16x8*)&sB[rowB * BK + g];
      }
#pragma unroll
      for (int mt = 0; mt < 4; ++mt)
#pragma unroll
        for (int nt = 0; nt < 4; ++nt)
          acc[mt][nt] = __builtin_amdgcn_mfma_f32_16x16x32_bf16(
              af[mt], bfv[nt], acc[mt][nt], 0, 0, 0);
    }
  }

#pragma unroll
  for (int mt = 0; mt < 4; ++mt) {
#pragma unroll
    for (int nt = 0; nt < 4; ++nt) {
      const size_t row_base = m0 + waveM * 64 + mt * 16 + quad * 4;
      const size_t col = n0 + waveN * 64 + nt * 16 + l16;
#pragma unroll
      for (int r = 0; r < 4; ++r) {
        const size_t row = row_base + r;
        float v = acc[mt][nt][r];
        if (MODE == 1) {
          v = gelu_f(v + bias[col]);
          ((bf16*)out)[row * N + col] = (bf16)v;
        } else if (MODE == 2) {
          v += bias[col] + resid[row * N + col];
          ((float*)out)[row * N + col] = v;
        } else {
          ((bf16*)out)[row * N + col] = (bf16)v;
        }
      }
    }
  }
}

// ---------------------------------------------------------------------------
// Flash-style causal attention (unchanged from round 2).
// ---------------------------------------------------------------------------
__global__ __launch_bounds__(256) void attn_kernel(
    const bf16* __restrict__ QKV, bf16* __restrict__ O) {
  const int idx = blockIdx.x;
  const int qt = 31 - (idx >> 6);
  const int bh = idx & 63;
  const int b = bh >> 4, h = bh & 15;
  const int t = threadIdx.x;
  const int lane = t & 63, wid = t >> 6;
  const int quad = lane >> 4, l16 = lane & 15;

  __shared__ bf16 sQ[64][72];
  __shared__ bf16 sK[64][72];
  __shared__ bf16 sVt[64][72];
  __shared__ bf16 sP[4][16][72];

  const size_t qbase = (size_t)b * 2048 * 3072 + (size_t)h * 64;
  const size_t kbase = qbase + 1024;
  const size_t vbase = qbase + 2048;
  const int q0 = qt * 64;

  for (int c = t; c < 512; c += 256) {
    int row = c >> 3, sub = (c & 7) * 8;
    *(bf16x8*)&sQ[row][sub] =
        *(const bf16x8*)(QKV + qbase + (size_t)(q0 + row) * 3072 + sub);
  }
  __syncthreads();

  bf16x8 aq[2];
  aq[0] = *(const bf16x8*)&sQ[wid * 16 + l16][quad * 8];
  aq[1] = *(const bf16x8*)&sQ[wid * 16 + l16][32 + quad * 8];

  float l_part[4] = {0.f, 0.f, 0.f, 0.f};
  floatx4 o_acc[4] = {};

  for (int kt = 0; kt <= qt; ++kt) {
    __syncthreads();
    const int k0 = kt * 64;
    for (int c = t; c < 512; c += 256) {
      int row = c >> 3, sub = (c & 7) * 8;
      *(bf16x8*)&sK[row][sub] =
          *(const bf16x8*)(QKV + kbase + (size_t)(k0 + row) * 3072 + sub);
      bf16x8 v8 = *(const bf16x8*)(QKV + vbase + (size_t)(k0 + row) * 3072 + sub);
#pragma unroll
      for (int j = 0; j < 8; ++j)
        sVt[sub + j][row ^ (sub & 56)] = v8[j];
    }
    __syncthreads();

    float p[4][4];
#pragma unroll
    for (int nt = 0; nt < 4; ++nt) {
      floatx4 acc = {};
#pragma unroll
      for (int ks = 0; ks < 2; ++ks) {
        bf16x8 bk = *(const bf16x8*)&sK[nt * 16 + l16][ks * 32 + quad * 8];
        acc = __builtin_amdgcn_mfma_f32_16x16x32_bf16(aq[ks], bk, acc, 0, 0, 0);
      }
#pragma unroll
      for (int r = 0; r < 4; ++r) p[nt][r] = exp2f(acc[r] * EXPC);
    }

    if (kt == qt) {
      const int qrow_base = q0 + wid * 16 + quad * 4;
#pragma unroll
      for (int nt = 0; nt < 4; ++nt) {
        const int kk = k0 + nt * 16 + l16;
#pragma unroll
        for (int r = 0; r < 4; ++r)
          if (kk > qrow_base + r) p[nt][r] = 0.f;
      }
    }

#pragma unroll
    for (int nt = 0; nt < 4; ++nt)
#pragma unroll
      for (int r = 0; r < 4; ++r) {
        l_part[r] += p[nt][r];
        sP[wid][quad * 4 + r][nt * 16 + l16] = (bf16)p[nt][r];
      }

    bf16x8 ap[2];
    ap[0] = *(const bf16x8*)&sP[wid][l16][quad * 8];
    ap[1] = *(const bf16x8*)&sP[wid][l16][32 + quad * 8];
#pragma unroll
    for (int nt = 0; nt < 4; ++nt) {
      const int r2 = nt * 16 + l16;
#pragma unroll
      for (int ks = 0; ks < 2; ++ks) {
        bf16x8 bv =
            *(const bf16x8*)&sVt[r2][(ks * 32 + quad * 8) ^ (r2 & 56)];
        o_acc[nt] =
            __builtin_amdgcn_mfma_f32_16x16x32_bf16(ap[ks], bv, o_acc[nt], 0, 0, 0);
      }
    }
  }

#pragma unroll
  for (int off = 1; off < 16; off <<= 1)
#pragma unroll
    for (int r = 0; r < 4; ++r) l_part[r] += __shfl_xor(l_part[r], off);
  float inv[4];
#pragma unroll
  for (int r = 0; r < 4; ++r) inv[r] = 1.0f / l_part[r];

#pragma unroll
  for (int nt = 0; nt < 4; ++nt)
#pragma unroll
    for (int r = 0; r < 4; ++r) {
      const size_t row = (size_t)b * 2048 + q0 + wid * 16 + quad * 4 + r;
      const size_t col = (size_t)h * 64 + nt * 16 + l16;
      O[row * 1024 + col] = (bf16)(o_acc[nt][r] * inv[r]);
    }
}

// ---------------------------------------------------------------------------
// Launch
// ---------------------------------------------------------------------------
extern "C" void kernel_launch(void* const* d_in, const int* in_sizes, int n_in,
                              void* d_out, int out_size, void* d_ws, size_t ws_size,
                              hipStream_t stream) {
  const float* x = (const float*)d_in[0];
  const float* Wq = (const float*)d_in[1];
  const float* Wk = (const float*)d_in[2];
  const float* Wv = (const float*)d_in[3];
  const float* Wo = (const float*)d_in[4];
  const float* bo = (const float*)d_in[5];
  const float* W1 = (const float*)d_in[6];
  const float* b1 = (const float*)d_in[7];
  const float* W2 = (const float*)d_in[8];
  const float* b2 = (const float*)d_in[9];
  const float* gamma1 = (const float*)d_in[10];
  const float* beta1 = (const float*)d_in[11];
  const float* gamma2 = (const float*)d_in[12];
  const float* beta2 = (const float*)d_in[13];

  char* ws = (char*)d_ws;
  const size_t MB = (size_t)1 << 20;
  bf16* WqkvT = (bf16*)(ws + 0 * MB);
  bf16* WoT = (bf16*)(ws + 6 * MB);
  bf16* W1T = (bf16*)(ws + 8 * MB);
  bf16* W2T = (bf16*)(ws + 16 * MB);
  bf16* h1  = (bf16*)(ws + 24 * MB);
  bf16* QKVb = (bf16*)(ws + 40 * MB);
  bf16* attnb = (bf16*)(ws + 88 * MB);
  float* x1 = (float*)(ws + 104 * MB);
  bf16* h2  = (bf16*)(ws + 136 * MB);
  bf16* midb = (bf16*)(ws + 152 * MB);

  dim3 blk(256);

  transpose_cvt4<<<dim3(32, 32, 4), blk, 0, stream>>>(
      Wq, Wk, Wv, Wo, WqkvT, WqkvT + (size_t)1024 * 1024,
      WqkvT + (size_t)2048 * 1024, WoT, 1024, 1024);
  transpose_cvt<<<dim3(128, 32), blk, 0, stream>>>(W1, W1T, 1024, 4096);
  transpose_cvt<<<dim3(32, 128), blk, 0, stream>>>(W2, W2T, 4096, 1024);

  ln_kernel<<<8192, blk, 0, stream>>>(x, gamma1, beta1, h1);

  // fused QKV projection: [Q|K|V] = h1 @ [Wq|Wk|Wv]  (block-rich: BK=64)
  gemm_bt<3, 64><<<dim3(64, 24), blk, 0, stream>>>(h1, WqkvT, nullptr, nullptr,
                                                   QKVb, 8192, 3072, 1024);

  attn_kernel<<<dim3(2048), blk, 0, stream>>>(QKVb, attnb);

  // x1 = x + attn @ Wo + bo  (grid-starved: BK=128, 8 barrier drains)
  gemm_bt<2, 128><<<dim3(64, 8), blk, 0, stream>>>(attnb, WoT, bo, x, x1,
                                                   8192, 1024, 1024);

  ln_kernel<<<8192, blk, 0, stream>>>(x1, gamma2, beta2, h2);

  // mid = gelu(h2 @ W1 + b1)  (block-rich: BK=64, fast gelu)
  gemm_bt<1, 64><<<dim3(64, 32), blk, 0, stream>>>(h2, W1T, b1, nullptr, midb,
                                                   8192, 4096, 1024);

  // out = x1 + mid @ W2 + b2  (grid-starved: BK=128, 32 barrier drains)
  gemm_bt<2, 128><<<dim3(64, 8), blk, 0, stream>>>(midb, W2T, b2, x1, d_out,
                                                   8192, 1024, 4096);
}